// Round 2
// baseline (1037.638 us; speedup 1.0000x reference)
//
#include <hip/hip_runtime.h>
#include <hip/hip_bf16.h>

// All inputs/outputs are float32 per the reference (round-1 NaN = f32 read as bf16).

__device__ __forceinline__ float gelu_f(float v){ return 0.5f*v*(1.0f + erff(v*0.70710678118654752f)); }

// ---------- generic tiled GEMM: C[M,N] = A[M,K] @ B[K,N] + bias ----------
// MODE 0: plain   MODE 1: batched over blockIdx.z (strides sB/sBias/sC)
// MODE 2: split-K over blockIdx.z (chunk Kc, atomicAdd into pre-zeroed C, bias added by z==0)
template<int MODE>
__global__ __launch_bounds__(256) void gemm_k(
    const float* __restrict__ A, const float* __restrict__ B, const float* __restrict__ bias,
    float* __restrict__ C, int M, int N, int K, long sB, long sBias, long sC, int Kc)
{
  const int bz = blockIdx.z;
  if constexpr (MODE==1){ B += sB*bz; bias += sBias*bz; C += sC*bz; }
  int klo = 0, khi = K;
  if constexpr (MODE==2){ klo = bz*Kc; khi = klo + Kc; }

  __shared__ __align__(16) float As[16][68];
  __shared__ __align__(16) float Bs[16][68];
  const int tid = threadIdx.x;
  const int m0 = blockIdx.y*64, n0 = blockIdx.x*64;
  const int ty = tid>>4, tx = tid&15;          // 4x4 micro-tile owner
  const int ar = tid>>2, ac = (tid&3)*4;       // A-tile load: row, 4 consecutive k
  const int kr = tid>>4, nc = (tid&15)*4;      // B-tile load: k-row, 4 consecutive n
  float acc[4][4] = {};
  const float* Ap = A + (long)(m0+ar)*K;

  for (int k0 = klo; k0 < khi; k0 += 16){
    float4 av = *(const float4*)(Ap + k0 + ac);
    float4 bv = *(const float4*)(B + (long)(k0+kr)*N + (n0+nc));
    __syncthreads();                       // previous iteration's compute done
    As[ac+0][ar] = av.x; As[ac+1][ar] = av.y; As[ac+2][ar] = av.z; As[ac+3][ar] = av.w;
    *(float4*)&Bs[kr][nc] = bv;
    __syncthreads();
    #pragma unroll
    for (int k = 0; k < 16; k++){
      float4 a4 = *(const float4*)&As[k][ty*4];
      float4 b4 = *(const float4*)&Bs[k][tx*4];
      float a[4] = {a4.x,a4.y,a4.z,a4.w};
      float b[4] = {b4.x,b4.y,b4.z,b4.w};
      #pragma unroll
      for (int i = 0; i < 4; i++)
        #pragma unroll
        for (int j = 0; j < 4; j++)
          acc[i][j] = fmaf(a[i], b[j], acc[i][j]);
    }
  }

  float bv4[4];
  #pragma unroll
  for (int j = 0; j < 4; j++) bv4[j] = bias[n0 + tx*4 + j];
  #pragma unroll
  for (int i = 0; i < 4; i++){
    long row = m0 + ty*4 + i;
    #pragma unroll
    for (int j = 0; j < 4; j++){
      float v = acc[i][j];
      if constexpr (MODE==2){
        if (bz == 0) v += bv4[j];
        atomicAdd(&C[row*(long)N + n0 + tx*4 + j], v);
      } else {
        C[row*(long)N + n0 + tx*4 + j] = v + bv4[j];
      }
    }
  }
}

// ---------- column mean over 4096 rows of adapt[4096,128] ----------
__global__ __launch_bounds__(256) void colmean_k(const float* __restrict__ adapt, float* __restrict__ am){
  __shared__ float red[256];
  int a = blockIdx.x, tid = threadIdx.x;
  float s = 0.f;
  for (int n = tid; n < 4096; n += 256) s += adapt[n*128 + a];
  red[tid] = s; __syncthreads();
  for (int w = 128; w > 0; w >>= 1){ if (tid < w) red[tid] += red[tid+w]; __syncthreads(); }
  if (tid == 0) am[a] = red[0] * (1.0f/4096.0f);
}

// ---------- gate = softmax(adapt @ Wg + bg), 5 outputs/token ----------
__global__ __launch_bounds__(256) void gate_k(const float* __restrict__ adapt,
    const float* __restrict__ Wg, const float* __restrict__ bg, float* __restrict__ gate){
  __shared__ float wg[640]; __shared__ float bgs[5];
  int tid = threadIdx.x;
  for (int i = tid; i < 640; i += 256) wg[i] = Wg[i];
  if (tid < 5) bgs[tid] = bg[tid];
  __syncthreads();
  int n = blockIdx.x*256 + tid;
  float l[5] = {bgs[0],bgs[1],bgs[2],bgs[3],bgs[4]};
  const float* ar = adapt + (long)n*128;
  for (int a = 0; a < 128; a++){
    float av = ar[a];
    #pragma unroll
    for (int e = 0; e < 5; e++) l[e] = fmaf(av, wg[a*5+e], l[e]);
  }
  float mx = l[0];
  #pragma unroll
  for (int e = 1; e < 5; e++) mx = fmaxf(mx, l[e]);
  float sum = 0.f;
  #pragma unroll
  for (int e = 0; e < 5; e++){ l[e] = expf(l[e]-mx); sum += l[e]; }
  float inv = 1.0f/sum;
  #pragma unroll
  for (int e = 0; e < 5; e++) gate[(long)n*5+e] = l[e]*inv;
}

// ---------- dynamic weights: Wdyn[seg][m] = W[m] + ba[m] + sum_a am[a]*Wa[a,m] ----------
__global__ __launch_bounds__(256) void dynw_k(const float* __restrict__ am,
    const float* Wt, const float* Wt_a, const float* bt_a,
    const float* Wc, const float* Wc_a, const float* bc_a,
    const float* We, const float* We_a, const float* be_a,
    float* __restrict__ Wdyn)
{
  __shared__ float ams[128];
  int tid = threadIdx.x;
  if (tid < 128) ams[tid] = am[tid];
  __syncthreads();
  long gid = (long)blockIdx.x*256 + tid;       // 0 .. 6*65536
  int seg = (int)(gid >> 16); int m = (int)(gid & 65535);
  const float *W, *Wa, *ba;
  if (seg == 0){ W = Wt; Wa = Wt_a; ba = bt_a; }
  else if (seg == 1){ W = Wc; Wa = Wc_a; ba = bc_a; }
  else { int e = seg-2; W = We + (long)e*65536; Wa = We_a + (long)e*65536*128; ba = be_a + (long)e*65536; }
  float s = W[m] + ba[m];
  for (int a = 0; a < 128; a++) s = fmaf(ams[a], Wa[(long)a*65536 + m], s);
  Wdyn[gid] = s;
}

// ---------- bias table for batched liquid GEMM ----------
__global__ void bias6_k(const float* bt, const float* bc, const float* be, float* bias6){
  int z = blockIdx.x, t = threadIdx.x;
  const float* s = (z==0) ? bt : (z==1) ? bc : be + (long)(z-2)*256;
  bias6[z*256 + t] = s[t];
}

// ---------- fused psi1: h1 += phi(x)@Wpsi1, phi = gelu(x_d*Wphi[d,k]+bphi[d,k]) ----------
// grid (64 token-blocks, 8 d-chunks of 32); BM=64 tokens, N=64 cols, K-chunk = 32 d * 64 k
__global__ __launch_bounds__(256) void psi1_k(const float* __restrict__ xf,
    const float* __restrict__ Wphi, const float* __restrict__ bphi,
    const float* __restrict__ Wpsi1, float* __restrict__ h1)
{
  __shared__ __align__(16) float xs[64][33];
  __shared__ __align__(16) float As[64][68];   // As[k][token]
  __shared__ __align__(16) float Bs[64][68];   // Bs[k][col]
  const int tid = threadIdx.x;
  const int m0 = blockIdx.x*64;
  const int d_lo = blockIdx.y*32;
  { // stage x tile: 64 tokens x 32 d
    int t = tid>>2, dq = (tid&3)*8;
    const float* src = xf + (long)(m0+t)*256 + d_lo + dq;
    #pragma unroll
    for (int i = 0; i < 8; i++) xs[t][dq+i] = src[i];
  }
  const int ty = tid>>4, tx = tid&15;
  const int k_a = tid>>2, t0_a = (tid&3)*16;   // phi compute mapping
  float acc[4][4] = {};
  __syncthreads();
  for (int dd = 0; dd < 32; dd++){
    int d = d_lo + dd;
    const float* wp = Wpsi1 + (long)d*4096;    // 64 contiguous rows of 64
    float w  = Wphi[d*64 + k_a];
    float bb = bphi[d*64 + k_a];
    __syncthreads();                           // previous compute done
    #pragma unroll
    for (int i = 0; i < 16; i++){
      int idx = tid + 256*i;                   // coalesced
      Bs[idx>>6][idx&63] = wp[idx];
    }
    #pragma unroll
    for (int i = 0; i < 16; i++){
      float xv = xs[t0_a+i][dd];
      As[k_a][t0_a+i] = gelu_f(fmaf(xv, w, bb));
    }
    __syncthreads();
    #pragma unroll
    for (int kk = 0; kk < 64; kk++){
      float4 a4 = *(const float4*)&As[kk][ty*4];
      float4 b4 = *(const float4*)&Bs[kk][tx*4];
      float a[4] = {a4.x,a4.y,a4.z,a4.w};
      float b[4] = {b4.x,b4.y,b4.z,b4.w};
      #pragma unroll
      for (int i = 0; i < 4; i++)
        #pragma unroll
        for (int j = 0; j < 4; j++)
          acc[i][j] = fmaf(a[i], b[j], acc[i][j]);
    }
  }
  #pragma unroll
  for (int i = 0; i < 4; i++)
    #pragma unroll
    for (int j = 0; j < 4; j++)
      atomicAdd(&h1[(long)(m0 + ty*4 + i)*64 + tx*4 + j], acc[i][j]);
}

// ---------- h1g = gelu(h1 + bpsi1) ----------
__global__ __launch_bounds__(256) void h1g_k(const float* __restrict__ h1,
    const float* __restrict__ bpsi1, float* __restrict__ h1g){
  int i = blockIdx.x*256 + threadIdx.x;
  h1g[i] = gelu_f(h1[i] + bpsi1[i & 63]);
}

// ---------- concat = [tok | chan | moe | lf] ----------
__global__ __launch_bounds__(256) void concat_k(const float* __restrict__ tok,
    const float* __restrict__ chan, const float* __restrict__ eo,
    const float* __restrict__ gate, const float* __restrict__ ka,
    const float* __restrict__ lf, float* __restrict__ concat)
{
  int n = blockIdx.x, tid = threadIdx.x;
  const float* g = gate + (long)n*5;
  float g0=g[0], g1=g[1], g2=g[2], g3=g[3], g4=g[4];
  long nb = (long)n*1536;
  int d = tid;  // 256 threads cover 256 exactly
  concat[nb + d]        = tok[(long)n*256 + d];
  concat[nb + 256 + d]  = chan[(long)n*256 + d];
  float m = g0*eo[(long)n*256 + d]
          + g1*eo[1048576 + (long)n*256 + d]
          + g2*eo[2097152 + (long)n*256 + d]
          + g3*eo[3145728 + (long)n*256 + d]
          + g4*ka[(long)n*256 + d];
  concat[nb + 512 + d] = m;
  for (int j = tid; j < 768; j += 256) concat[nb + 768 + j] = lf[(long)n*768 + j];
}

// ---------- cw = softmax( gelu(h_pre) @ W2 + b2 ) ----------
__global__ __launch_bounds__(256) void cw_k(const float* __restrict__ hpre,
    const float* __restrict__ W2, const float* __restrict__ b2, float* __restrict__ cw){
  __shared__ float w2s[256]; __shared__ float b2s[4];
  int tid = threadIdx.x;
  w2s[tid] = W2[tid];
  if (tid < 4) b2s[tid] = b2[tid];
  __syncthreads();
  int n = blockIdx.x*256 + tid;
  float l[4] = {b2s[0],b2s[1],b2s[2],b2s[3]};
  const float* hp = hpre + (long)n*64;
  for (int j = 0; j < 64; j++){
    float hj = gelu_f(hp[j]);
    #pragma unroll
    for (int c = 0; c < 4; c++) l[c] = fmaf(hj, w2s[j*4+c], l[c]);
  }
  float mx = fmaxf(fmaxf(l[0],l[1]), fmaxf(l[2],l[3]));
  float sum = 0.f;
  #pragma unroll
  for (int c = 0; c < 4; c++){ l[c] = expf(l[c]-mx); sum += l[c]; }
  float inv = 1.0f/sum;
  #pragma unroll
  for (int c = 0; c < 4; c++) cw[(long)n*4+c] = l[c]*inv;
}

// ---------- combined (in-place on concat) = cw[seg]*concat + residual ----------
__global__ __launch_bounds__(256) void combine_k(float* __restrict__ concat,
    const float* __restrict__ residual, const float* __restrict__ cw){
  int n = blockIdx.x;
  int j = blockIdx.y*256 + threadIdx.x;
  int seg = (j < 768) ? (j >> 8) : 3;
  long idx = (long)n*1536 + j;
  concat[idx] = fmaf(cw[(long)n*4 + seg], concat[idx], residual[idx]);
}

// ---------- launch ----------
extern "C" void kernel_launch(void* const* d_in, const int* in_sizes, int n_in,
                              void* d_out, int out_size, void* d_ws, size_t ws_size,
                              hipStream_t stream)
{
  const float* x      = (const float*)d_in[0];
  const float* lf     = (const float*)d_in[1];
  const float* W_feat = (const float*)d_in[2];
  const float* b_feat = (const float*)d_in[3];
  const float* Wt     = (const float*)d_in[4];
  const float* bt     = (const float*)d_in[5];
  const float* Wt_a   = (const float*)d_in[6];
  const float* bt_a   = (const float*)d_in[7];
  const float* Wc     = (const float*)d_in[8];
  const float* bc     = (const float*)d_in[9];
  const float* Wc_a   = (const float*)d_in[10];
  const float* bc_a   = (const float*)d_in[11];
  const float* We     = (const float*)d_in[12];
  const float* be     = (const float*)d_in[13];
  const float* We_a   = (const float*)d_in[14];
  const float* be_a   = (const float*)d_in[15];
  const float* Wg     = (const float*)d_in[16];
  const float* bg     = (const float*)d_in[17];
  const float* Wphi   = (const float*)d_in[18];
  const float* bphi   = (const float*)d_in[19];
  const float* Wpsi1  = (const float*)d_in[20];
  const float* bpsi1  = (const float*)d_in[21];
  const float* Wpsi2  = (const float*)d_in[22];
  const float* bpsi2  = (const float*)d_in[23];
  const float* Wres   = (const float*)d_in[24];
  const float* bres   = (const float*)d_in[25];
  const float* W1     = (const float*)d_in[26];
  const float* b1     = (const float*)d_in[27];
  const float* W2     = (const float*)d_in[28];
  const float* b2     = (const float*)d_in[29];
  const float* Wo     = (const float*)d_in[30];
  const float* bo     = (const float*)d_in[31];

  float* ws = (float*)d_ws;
  float* T      = ws;                        // 6 x 1,048,576 : tok|chan|eo[0..3]
  float* tok    = T;
  float* chan   = T + 1048576;
  float* eo     = T + 2*1048576;
  float* adapt  = T + 6*1048576;             // 524,288
  float* am     = adapt + 524288;            // 128
  float* gate   = am + 128;                  // 20,480
  float* Wdyn   = gate + 20480;              // 393,216
  float* bias6  = Wdyn + 393216;             // 1,536
  float* h1     = bias6 + 1536;              // 262,144
  float* h1g    = h1 + 262144;               // 262,144
  float* ka     = h1g + 262144;              // 1,048,576
  float* concat = ka + 1048576;              // 6,291,456  (~60.5 MB total)
  float* residual = T;                       // alias: tok/chan/eo dead after concat_k
  float* hpre   = adapt;                     // alias: adapt dead after colmean/gate
  float* cw     = adapt + 262144;            // alias: fits inside adapt region

  dim3 b256(256);

  // adapt = x @ W_feat + b_feat          [4096,128] K=256
  gemm_k<0><<<dim3(2,64,1), b256, 0, stream>>>(
      x, W_feat, b_feat, adapt, 4096,128,256, 0,0,0,0);

  colmean_k<<<dim3(128), b256, 0, stream>>>(adapt, am);
  gate_k<<<dim3(16), b256, 0, stream>>>(adapt, Wg, bg, gate);

  dynw_k<<<dim3(1536), b256, 0, stream>>>(am, Wt,Wt_a,bt_a, Wc,Wc_a,bc_a, We,We_a,be_a, Wdyn);
  bias6_k<<<dim3(6), b256, 0, stream>>>(bt, bc, be, bias6);

  // tok/chan/eo[e] = x @ Wdyn[z] + bias6[z]   batched z=0..5, [4096,256] K=256
  gemm_k<1><<<dim3(4,64,6), b256, 0, stream>>>(
      x, Wdyn, bias6, T, 4096,256,256, 65536,256,1048576, 0);

  // KA expert: h1 = phi @ Wpsi1 (split-K atomics), then gelu(+bpsi1), then @ Wpsi2
  hipMemsetAsync(h1, 0, 262144*sizeof(float), stream);
  psi1_k<<<dim3(64,8), b256, 0, stream>>>(x, Wphi, bphi, Wpsi1, h1);
  h1g_k<<<dim3(1024), b256, 0, stream>>>(h1, bpsi1, h1g);
  gemm_k<0><<<dim3(4,64,1), b256, 0, stream>>>(
      h1g, Wpsi2, bpsi2, ka, 4096,256,64, 0,0,0,0);

  concat_k<<<dim3(4096), b256, 0, stream>>>(tok, chan, eo, gate, ka, lf, concat);

  // residual = concat @ Wres + bres       [4096,1536] K=1536
  gemm_k<0><<<dim3(24,64,1), b256, 0, stream>>>(
      concat, Wres, bres, residual, 4096,1536,1536, 0,0,0,0);

  // h_pre = concat @ W1 + b1 (split-K=8, bias by z0; gelu folded into cw_k)
  hipMemsetAsync(hpre, 0, 262144*sizeof(float), stream);
  gemm_k<2><<<dim3(1,64,8), b256, 0, stream>>>(
      concat, W1, b1, hpre, 4096,64,1536, 0,0,0, 192);
  cw_k<<<dim3(16), b256, 0, stream>>>(hpre, W2, b2, cw);

  combine_k<<<dim3(4096,6), b256, 0, stream>>>(concat, residual, cw);

  // out = combined @ Wo + bo              [4096,256] K=1536
  gemm_k<0><<<dim3(4,64,1), b256, 0, stream>>>(
      concat, Wo, bo, (float*)d_out, 4096,256,1536, 0,0,0,0);
}

// Round 3
// 744.028 us; speedup vs baseline: 1.3946x; 1.3946x over previous
//
#include <hip/hip_runtime.h>
#include <hip/hip_bf16.h>

// fp32 in/out; big GEMMs via bf16 MFMA (16x16x32), fp32 accumulate.

__device__ __forceinline__ float gelu_f(float v){ return 0.5f*v*(1.0f + erff(v*0.70710678118654752f)); }

__device__ __forceinline__ float u16tof(unsigned short u){
  union { unsigned int i; float f; } v; v.i = ((unsigned int)u) << 16; return v.f;
}
__device__ __forceinline__ unsigned short f2b(float f){   // RNE f32->bf16
  union { float f; unsigned int u; } v; v.f = f;
  unsigned int r = v.u + 0x7fffu + ((v.u >> 16) & 1u);
  return (unsigned short)(r >> 16);
}

using short8  = __attribute__((ext_vector_type(8))) short;
using float4v = __attribute__((ext_vector_type(4))) float;

// ================= bf16 MFMA GEMM =================
// C[M,N](f32) = A[M,K](bf16) @ Bt[N,K](bf16)^T + bias[N](f32)
// MODE 0 plain; MODE 1 batched over blockIdx.z (sB/sBias/sC strides)
// Tile BM=128 BN=128 BK=32; 256 thr = 4 waves, each wave a 64x64 quadrant (4x4 MFMA tiles).
template<int MODE>
__global__ __launch_bounds__(256) void mgemm_k(
    const unsigned short* __restrict__ A, const unsigned short* __restrict__ Bt,
    const float* __restrict__ bias, float* __restrict__ C,
    int M, int N, int K, long sB, long sBias, long sC)
{
  if constexpr (MODE==1){
    Bt   += sB   * blockIdx.z;
    bias += sBias* blockIdx.z;
    C    += sC   * blockIdx.z;
  }
  __shared__ __align__(16) unsigned short As[128][40];
  __shared__ __align__(16) unsigned short Bs[128][40];
  const int tid  = threadIdx.x;
  const int m0   = blockIdx.y*128, n0 = blockIdx.x*128;
  const int wave = tid>>6, lane = tid&63;
  const int wm   = (wave&1)*64, wn = (wave>>1)*64;
  const int q    = lane>>4, r = lane&15;
  const int sm   = tid>>2, sq = (tid&3)*8;   // staging: row, chunk elem-offset

  float4v acc[4][4];
  #pragma unroll
  for (int i=0;i<4;i++)
    #pragma unroll
    for (int j=0;j<4;j++) acc[i][j] = (float4v){0.f,0.f,0.f,0.f};

  const unsigned short* Ap = A + (long)(m0+sm)*K + sq;
  const unsigned short* Bp = Bt + (long)(n0+sm)*K + sq;
  const long rstep = (long)64*K;

  for (int k0 = 0; k0 < K; k0 += 32){
    uint4 a0 = *(const uint4*)(Ap + k0);
    uint4 a1 = *(const uint4*)(Ap + k0 + rstep);
    uint4 b0 = *(const uint4*)(Bp + k0);
    uint4 b1 = *(const uint4*)(Bp + k0 + rstep);
    __syncthreads();                          // previous iter's reads done
    *(uint4*)&As[sm   ][sq] = a0;
    *(uint4*)&As[sm+64][sq] = a1;
    *(uint4*)&Bs[sm   ][sq] = b0;
    *(uint4*)&Bs[sm+64][sq] = b1;
    __syncthreads();
    short8 af[4], bf[4];
    #pragma unroll
    for (int mt=0;mt<4;mt++) af[mt] = *(const short8*)&As[wm + mt*16 + r][q*8];
    #pragma unroll
    for (int nt=0;nt<4;nt++) bf[nt] = *(const short8*)&Bs[wn + nt*16 + r][q*8];
    #pragma unroll
    for (int mt=0;mt<4;mt++)
      #pragma unroll
      for (int nt=0;nt<4;nt++)
        acc[mt][nt] = __builtin_amdgcn_mfma_f32_16x16x32_bf16(af[mt], bf[nt], acc[mt][nt], 0, 0, 0);
  }

  #pragma unroll
  for (int nt=0;nt<4;nt++){
    int col = n0 + wn + nt*16 + r;
    float bb = bias[col];
    #pragma unroll
    for (int mt=0;mt<4;mt++){
      #pragma unroll
      for (int i=0;i<4;i++){
        int row = m0 + wm + mt*16 + q*4 + i;
        C[(long)row*N + col] = acc[mt][nt][i] + bb;
      }
    }
  }
}

// ================= convert helpers =================
// x f32 -> bf16 row-major (A operand). n = total elems / 4
__global__ __launch_bounds__(256) void cvtb_k(const float* __restrict__ in, unsigned short* __restrict__ out){
  int i = (blockIdx.x*256 + threadIdx.x)*4;
  float4 v = *(const float4*)(in + i);
  ushort4 o; o.x = f2b(v.x); o.y = f2b(v.y); o.z = f2b(v.z); o.w = f2b(v.w);
  *(ushort4*)(out + i) = o;
}

// transpose-convert: in[R][C] f32 -> out[C][R] bf16   grid (C/64, R/64)
__global__ __launch_bounds__(256) void tconv_k(const float* __restrict__ in, unsigned short* __restrict__ out, int R, int C){
  __shared__ float t[64][65];
  const int tid = threadIdx.x;
  const int c0 = blockIdx.x*64, r0 = blockIdx.y*64;
  const int lr = tid>>2, lc0 = (tid&3)*16;
  #pragma unroll
  for (int i=0;i<4;i++){
    float4 v = *(const float4*)&in[(long)(r0+lr)*C + c0 + lc0 + i*4];
    t[lr][lc0+i*4+0]=v.x; t[lr][lc0+i*4+1]=v.y; t[lr][lc0+i*4+2]=v.z; t[lr][lc0+i*4+3]=v.w;
  }
  __syncthreads();
  const int oc = tid>>2, os = (tid&3)*16;
  #pragma unroll
  for (int i=0;i<16;i++)
    out[(long)(c0+oc)*R + r0 + os + i] = f2b(t[os+i][oc]);
}

// ================= SIMT fp32 GEMM (small shapes) =================
__device__ __forceinline__ float4 ld4(const float* p){ return *(const float4*)p; }
__device__ __forceinline__ float4 ld4(const unsigned short* p){
  ushort4 u = *(const ushort4*)p;
  return make_float4(u16tof(u.x), u16tof(u.y), u16tof(u.z), u16tof(u.w));
}
// MODE 0: plain   MODE 2: split-K over blockIdx.z (chunk Kc, atomicAdd, bias by z==0)
template<typename AT, int MODE>
__global__ __launch_bounds__(256) void gemm_k(
    const AT* __restrict__ A, const float* __restrict__ B, const float* __restrict__ bias,
    float* __restrict__ C, int M, int N, int K, int Kc)
{
  int klo = 0, khi = K;
  if constexpr (MODE==2){ klo = blockIdx.z*Kc; khi = klo + Kc; }
  __shared__ __align__(16) float As[16][68];
  __shared__ __align__(16) float Bs[16][68];
  const int tid = threadIdx.x;
  const int m0 = blockIdx.y*64, n0 = blockIdx.x*64;
  const int ty = tid>>4, tx = tid&15;
  const int ar = tid>>2, ac = (tid&3)*4;
  const int kr = tid>>4, nc = (tid&15)*4;
  float acc[4][4] = {};
  const AT* Ap = A + (long)(m0+ar)*K;

  for (int k0 = klo; k0 < khi; k0 += 16){
    float4 av = ld4(Ap + k0 + ac);
    float4 bv = *(const float4*)(B + (long)(k0+kr)*N + (n0+nc));
    __syncthreads();
    As[ac+0][ar] = av.x; As[ac+1][ar] = av.y; As[ac+2][ar] = av.z; As[ac+3][ar] = av.w;
    *(float4*)&Bs[kr][nc] = bv;
    __syncthreads();
    #pragma unroll
    for (int k = 0; k < 16; k++){
      float4 a4 = *(const float4*)&As[k][ty*4];
      float4 b4 = *(const float4*)&Bs[k][tx*4];
      float a[4] = {a4.x,a4.y,a4.z,a4.w};
      float b[4] = {b4.x,b4.y,b4.z,b4.w};
      #pragma unroll
      for (int i = 0; i < 4; i++)
        #pragma unroll
        for (int j = 0; j < 4; j++)
          acc[i][j] = fmaf(a[i], b[j], acc[i][j]);
    }
  }
  float bv4[4];
  #pragma unroll
  for (int j = 0; j < 4; j++) bv4[j] = bias[n0 + tx*4 + j];
  #pragma unroll
  for (int i = 0; i < 4; i++){
    long row = m0 + ty*4 + i;
    #pragma unroll
    for (int j = 0; j < 4; j++){
      float v = acc[i][j];
      if constexpr (MODE==2){
        if (blockIdx.z == 0) v += bv4[j];
        atomicAdd(&C[row*(long)N + n0 + tx*4 + j], v);
      } else {
        C[row*(long)N + n0 + tx*4 + j] = v + bv4[j];
      }
    }
  }
}

// ---------- column mean over 4096 rows of adapt[4096,128] ----------
__global__ __launch_bounds__(256) void colmean_k(const float* __restrict__ adapt, float* __restrict__ am){
  __shared__ float red[256];
  int a = blockIdx.x, tid = threadIdx.x;
  float s = 0.f;
  for (int n = tid; n < 4096; n += 256) s += adapt[n*128 + a];
  red[tid] = s; __syncthreads();
  for (int w = 128; w > 0; w >>= 1){ if (tid < w) red[tid] += red[tid+w]; __syncthreads(); }
  if (tid == 0) am[a] = red[0] * (1.0f/4096.0f);
}

// ---------- gate = softmax(adapt @ Wg + bg) ----------
__global__ __launch_bounds__(256) void gate_k(const float* __restrict__ adapt,
    const float* __restrict__ Wg, const float* __restrict__ bg, float* __restrict__ gate){
  __shared__ float wg[640]; __shared__ float bgs[5];
  int tid = threadIdx.x;
  for (int i = tid; i < 640; i += 256) wg[i] = Wg[i];
  if (tid < 5) bgs[tid] = bg[tid];
  __syncthreads();
  int n = blockIdx.x*256 + tid;
  float l[5] = {bgs[0],bgs[1],bgs[2],bgs[3],bgs[4]};
  const float* ar = adapt + (long)n*128;
  for (int a = 0; a < 128; a++){
    float av = ar[a];
    #pragma unroll
    for (int e = 0; e < 5; e++) l[e] = fmaf(av, wg[a*5+e], l[e]);
  }
  float mx = l[0];
  #pragma unroll
  for (int e = 1; e < 5; e++) mx = fmaxf(mx, l[e]);
  float sum = 0.f;
  #pragma unroll
  for (int e = 0; e < 5; e++){ l[e] = expf(l[e]-mx); sum += l[e]; }
  float inv = 1.0f/sum;
  #pragma unroll
  for (int e = 0; e < 5; e++) gate[(long)n*5+e] = l[e]*inv;
}

// ---------- dynamic weights -> bf16 TRANSPOSED: Wdyn_t[z][out][in] ----------
__global__ __launch_bounds__(256) void dynw_k(const float* __restrict__ am,
    const float* Wt, const float* Wt_a, const float* bt_a,
    const float* Wc, const float* Wc_a, const float* bc_a,
    const float* We, const float* We_a, const float* be_a,
    unsigned short* __restrict__ Wdyn_t)
{
  __shared__ float ams[128];
  int tid = threadIdx.x;
  if (tid < 128) ams[tid] = am[tid];
  __syncthreads();
  long gid = (long)blockIdx.x*256 + tid;       // 0 .. 6*65536
  int seg = (int)(gid >> 16); int m = (int)(gid & 65535);
  const float *W, *Wa, *ba;
  if (seg == 0){ W = Wt; Wa = Wt_a; ba = bt_a; }
  else if (seg == 1){ W = Wc; Wa = Wc_a; ba = bc_a; }
  else { int e = seg-2; W = We + (long)e*65536; Wa = We_a + (long)e*65536*128; ba = be_a + (long)e*65536; }
  float s = W[m] + ba[m];
  for (int a = 0; a < 128; a++) s = fmaf(ams[a], Wa[(long)a*65536 + m], s);
  int row = m >> 8, col = m & 255;             // W[in=row][out=col]
  Wdyn_t[(long)seg*65536 + (long)col*256 + row] = f2b(s);
}

// ---------- bias table for batched liquid GEMM ----------
__global__ void bias6_k(const float* bt, const float* bc, const float* be, float* bias6){
  int z = blockIdx.x, t = threadIdx.x;
  const float* s = (z==0) ? bt : (z==1) ? bc : be + (long)(z-2)*256;
  bias6[z*256 + t] = s[t];
}

// ---------- fused psi1 (SIMT, unchanged) ----------
__global__ __launch_bounds__(256) void psi1_k(const float* __restrict__ xf,
    const float* __restrict__ Wphi, const float* __restrict__ bphi,
    const float* __restrict__ Wpsi1, float* __restrict__ h1)
{
  __shared__ __align__(16) float xs[64][33];
  __shared__ __align__(16) float As[64][68];
  __shared__ __align__(16) float Bs[64][68];
  const int tid = threadIdx.x;
  const int m0 = blockIdx.x*64;
  const int d_lo = blockIdx.y*32;
  {
    int t = tid>>2, dq = (tid&3)*8;
    const float* src = xf + (long)(m0+t)*256 + d_lo + dq;
    #pragma unroll
    for (int i = 0; i < 8; i++) xs[t][dq+i] = src[i];
  }
  const int ty = tid>>4, tx = tid&15;
  const int k_a = tid>>2, t0_a = (tid&3)*16;
  float acc[4][4] = {};
  __syncthreads();
  for (int dd = 0; dd < 32; dd++){
    int d = d_lo + dd;
    const float* wp = Wpsi1 + (long)d*4096;
    float w  = Wphi[d*64 + k_a];
    float bb = bphi[d*64 + k_a];
    __syncthreads();
    #pragma unroll
    for (int i = 0; i < 16; i++){
      int idx = tid + 256*i;
      Bs[idx>>6][idx&63] = wp[idx];
    }
    #pragma unroll
    for (int i = 0; i < 16; i++){
      float xv = xs[t0_a+i][dd];
      As[k_a][t0_a+i] = gelu_f(fmaf(xv, w, bb));
    }
    __syncthreads();
    #pragma unroll
    for (int kk = 0; kk < 64; kk++){
      float4 a4 = *(const float4*)&As[kk][ty*4];
      float4 b4 = *(const float4*)&Bs[kk][tx*4];
      float a[4] = {a4.x,a4.y,a4.z,a4.w};
      float b[4] = {b4.x,b4.y,b4.z,b4.w};
      #pragma unroll
      for (int i = 0; i < 4; i++)
        #pragma unroll
        for (int j = 0; j < 4; j++)
          acc[i][j] = fmaf(a[i], b[j], acc[i][j]);
    }
  }
  #pragma unroll
  for (int i = 0; i < 4; i++)
    #pragma unroll
    for (int j = 0; j < 4; j++)
      atomicAdd(&h1[(long)(m0 + ty*4 + i)*64 + tx*4 + j], acc[i][j]);
}

// ---------- h1g = gelu(h1 + bpsi1) ----------
__global__ __launch_bounds__(256) void h1g_k(const float* __restrict__ h1,
    const float* __restrict__ bpsi1, float* __restrict__ h1g){
  int i = blockIdx.x*256 + threadIdx.x;
  h1g[i] = gelu_f(h1[i] + bpsi1[i & 63]);
}

// ---------- concat -> bf16 [tok | chan | moe | lf] ----------
__global__ __launch_bounds__(256) void concat_k(const float* __restrict__ tok,
    const float* __restrict__ chan, const float* __restrict__ eo,
    const float* __restrict__ gate, const float* __restrict__ ka,
    const float* __restrict__ lf, unsigned short* __restrict__ concat)
{
  int n = blockIdx.x, tid = threadIdx.x;
  const float* g = gate + (long)n*5;
  float g0=g[0], g1=g[1], g2=g[2], g3=g[3], g4=g[4];
  long nb = (long)n*1536;
  int d = tid;
  concat[nb + d]        = f2b(tok[(long)n*256 + d]);
  concat[nb + 256 + d]  = f2b(chan[(long)n*256 + d]);
  float m = g0*eo[(long)n*256 + d]
          + g1*eo[1048576 + (long)n*256 + d]
          + g2*eo[2097152 + (long)n*256 + d]
          + g3*eo[3145728 + (long)n*256 + d]
          + g4*ka[(long)n*256 + d];
  concat[nb + 512 + d] = f2b(m);
  for (int j = tid; j < 768; j += 256) concat[nb + 768 + j] = f2b(lf[(long)n*768 + j]);
}

// ---------- cw = softmax( gelu(h_pre) @ W2 + b2 ) ----------
__global__ __launch_bounds__(256) void cw_k(const float* __restrict__ hpre,
    const float* __restrict__ W2, const float* __restrict__ b2, float* __restrict__ cw){
  __shared__ float w2s[256]; __shared__ float b2s[4];
  int tid = threadIdx.x;
  w2s[tid] = W2[tid];
  if (tid < 4) b2s[tid] = b2[tid];
  __syncthreads();
  int n = blockIdx.x*256 + tid;
  float l[4] = {b2s[0],b2s[1],b2s[2],b2s[3]};
  const float* hp = hpre + (long)n*64;
  for (int j = 0; j < 64; j++){
    float hj = gelu_f(hp[j]);
    #pragma unroll
    for (int c = 0; c < 4; c++) l[c] = fmaf(hj, w2s[j*4+c], l[c]);
  }
  float mx = fmaxf(fmaxf(l[0],l[1]), fmaxf(l[2],l[3]));
  float sum = 0.f;
  #pragma unroll
  for (int c = 0; c < 4; c++){ l[c] = expf(l[c]-mx); sum += l[c]; }
  float inv = 1.0f/sum;
  #pragma unroll
  for (int c = 0; c < 4; c++) cw[(long)n*4+c] = l[c]*inv;
}

// ---------- combined (in-place bf16) = bf16( cw[seg]*concat + residual ) ----------
__global__ __launch_bounds__(256) void combine_k(unsigned short* __restrict__ concat,
    const float* __restrict__ residual, const float* __restrict__ cw){
  int n = blockIdx.x;
  int j = blockIdx.y*256 + threadIdx.x;
  int seg = (j < 768) ? (j >> 8) : 3;
  long idx = (long)n*1536 + j;
  float v = fmaf(cw[(long)n*4 + seg], u16tof(concat[idx]), residual[idx]);
  concat[idx] = f2b(v);
}

// ---------- launch ----------
extern "C" void kernel_launch(void* const* d_in, const int* in_sizes, int n_in,
                              void* d_out, int out_size, void* d_ws, size_t ws_size,
                              hipStream_t stream)
{
  const float* x      = (const float*)d_in[0];
  const float* lf     = (const float*)d_in[1];
  const float* W_feat = (const float*)d_in[2];
  const float* b_feat = (const float*)d_in[3];
  const float* Wt     = (const float*)d_in[4];
  const float* bt     = (const float*)d_in[5];
  const float* Wt_a   = (const float*)d_in[6];
  const float* bt_a   = (const float*)d_in[7];
  const float* Wc     = (const float*)d_in[8];
  const float* bc     = (const float*)d_in[9];
  const float* Wc_a   = (const float*)d_in[10];
  const float* bc_a   = (const float*)d_in[11];
  const float* We     = (const float*)d_in[12];
  const float* be     = (const float*)d_in[13];
  const float* We_a   = (const float*)d_in[14];
  const float* be_a   = (const float*)d_in[15];
  const float* Wg     = (const float*)d_in[16];
  const float* bg     = (const float*)d_in[17];
  const float* Wphi   = (const float*)d_in[18];
  const float* bphi   = (const float*)d_in[19];
  const float* Wpsi1  = (const float*)d_in[20];
  const float* bpsi1  = (const float*)d_in[21];
  const float* Wpsi2  = (const float*)d_in[22];
  const float* bpsi2  = (const float*)d_in[23];
  const float* Wres   = (const float*)d_in[24];
  const float* bres   = (const float*)d_in[25];
  const float* W1     = (const float*)d_in[26];
  const float* b1     = (const float*)d_in[27];
  const float* W2     = (const float*)d_in[28];
  const float* b2     = (const float*)d_in[29];
  const float* Wo     = (const float*)d_in[30];
  const float* bo     = (const float*)d_in[31];

  float* ws = (float*)d_ws;
  float* T      = ws;                        // 6,291,456 f32 : tok|chan|eo[0..3]
  float* tok    = T;
  float* chan   = T + 1048576;
  float* eo     = T + 2*1048576;
  float* adapt  = T + 6*1048576;             // 524,288
  float* am     = adapt + 524288;            // 128
  float* gate   = am + 128;                  // 20,480
  float* bias6  = gate + 20480;              // 1,536
  float* h1     = bias6 + 1536;              // 262,144
  float* h1g    = h1 + 262144;               // 262,144
  float* ka     = h1g + 262144;              // 1,048,576
  unsigned short* xb     = (unsigned short*)(ka + 1048576);  // 1,048,576 u16
  unsigned short* Wdyn_t = xb + 1048576;                     // 393,216 u16
  unsigned short* Wres_t = Wdyn_t + 393216;                  // 2,359,296 u16
  unsigned short* Wo_t   = Wres_t + 2359296;                 // 393,216 u16
  unsigned short* concat = Wo_t + 393216;                    // 6,291,456 u16
  float* residual = T;                       // alias: tok/chan/eo dead after concat_k
  float* hpre   = adapt;                     // alias: adapt dead after colmean/gate
  float* cw     = adapt + 262144;            // alias

  dim3 b256(256);

  // converts
  cvtb_k<<<dim3(1024), b256, 0, stream>>>(x, xb);
  tconv_k<<<dim3(24,24), b256, 0, stream>>>(Wres, Wres_t, 1536, 1536);
  tconv_k<<<dim3(4,24),  b256, 0, stream>>>(Wo,   Wo_t,   1536, 256);

  // adapt = x @ W_feat + b_feat (fp32 SIMT for am precision)  [4096,128] K=256
  gemm_k<float,0><<<dim3(2,64,1), b256, 0, stream>>>(x, W_feat, b_feat, adapt, 4096,128,256, 0);

  colmean_k<<<dim3(128), b256, 0, stream>>>(adapt, am);
  gate_k<<<dim3(16), b256, 0, stream>>>(adapt, Wg, bg, gate);

  dynw_k<<<dim3(1536), b256, 0, stream>>>(am, Wt,Wt_a,bt_a, Wc,Wc_a,bc_a, We,We_a,be_a, Wdyn_t);
  bias6_k<<<dim3(6), b256, 0, stream>>>(bt, bc, be, bias6);

  // tok/chan/eo[z] = xb @ Wdyn_t[z]^T + bias6[z]   MFMA batched  [4096,256] K=256
  mgemm_k<1><<<dim3(2,32,6), b256, 0, stream>>>(xb, Wdyn_t, bias6, T, 4096,256,256, 65536,256,1048576);

  // KA expert (SIMT this round)
  hipMemsetAsync(h1, 0, 262144*sizeof(float), stream);
  psi1_k<<<dim3(64,8), b256, 0, stream>>>(x, Wphi, bphi, Wpsi1, h1);
  h1g_k<<<dim3(1024), b256, 0, stream>>>(h1, bpsi1, h1g);
  gemm_k<float,0><<<dim3(4,64,1), b256, 0, stream>>>(h1g, Wpsi2, bpsi2, ka, 4096,256,64, 0);

  concat_k<<<dim3(4096), b256, 0, stream>>>(tok, chan, eo, gate, ka, lf, concat);

  // residual = concat @ Wres + bres   MFMA  [4096,1536] K=1536
  mgemm_k<0><<<dim3(12,32,1), b256, 0, stream>>>(concat, Wres_t, bres, residual, 4096,1536,1536, 0,0,0);

  // h_pre = concat @ W1 + b1 (SIMT split-K=8; gelu folded into cw_k)
  hipMemsetAsync(hpre, 0, 262144*sizeof(float), stream);
  gemm_k<unsigned short,2><<<dim3(1,64,8), b256, 0, stream>>>(concat, W1, b1, hpre, 4096,64,1536, 192);
  cw_k<<<dim3(16), b256, 0, stream>>>(hpre, W2, b2, cw);

  combine_k<<<dim3(4096,6), b256, 0, stream>>>(concat, residual, cw);

  // out = combined @ Wo + bo   MFMA  [4096,256] K=1536
  mgemm_k<0><<<dim3(2,32,1), b256, 0, stream>>>(concat, Wo_t, bo, (float*)d_out, 4096,256,1536, 0,0,0);
}

// Round 4
// 626.991 us; speedup vs baseline: 1.6549x; 1.1867x over previous
//
#include <hip/hip_runtime.h>
#include <hip/hip_bf16.h>

// fp32 in/out; big GEMMs + KA expert via bf16 MFMA (16x16x32), fp32 accumulate.

__device__ __forceinline__ float gelu_f(float v){ return 0.5f*v*(1.0f + erff(v*0.70710678118654752f)); }

__device__ __forceinline__ float u16tof(unsigned short u){
  union { unsigned int i; float f; } v; v.i = ((unsigned int)u) << 16; return v.f;
}
__device__ __forceinline__ unsigned short f2b(float f){   // RNE f32->bf16
  union { float f; unsigned int u; } v; v.f = f;
  unsigned int r = v.u + 0x7fffu + ((v.u >> 16) & 1u);
  return (unsigned short)(r >> 16);
}

using short8  = __attribute__((ext_vector_type(8))) short;
using float4v = __attribute__((ext_vector_type(4))) float;

// ================= bf16 MFMA GEMM =================
// C[M,N](f32) = A[M,K](bf16) @ Bt[N,K](bf16)^T + bias[N](f32)
// MODE 0 plain; MODE 1 batched over blockIdx.z
template<int MODE>
__global__ __launch_bounds__(256) void mgemm_k(
    const unsigned short* __restrict__ A, const unsigned short* __restrict__ Bt,
    const float* __restrict__ bias, float* __restrict__ C,
    int M, int N, int K, long sB, long sBias, long sC)
{
  if constexpr (MODE==1){
    Bt   += sB   * blockIdx.z;
    bias += sBias* blockIdx.z;
    C    += sC   * blockIdx.z;
  }
  __shared__ __align__(16) unsigned short As[128][40];
  __shared__ __align__(16) unsigned short Bs[128][40];
  const int tid  = threadIdx.x;
  const int m0   = blockIdx.y*128, n0 = blockIdx.x*128;
  const int wave = tid>>6, lane = tid&63;
  const int wm   = (wave&1)*64, wn = (wave>>1)*64;
  const int q    = lane>>4, r = lane&15;
  const int sm   = tid>>2, sq = (tid&3)*8;

  float4v acc[4][4];
  #pragma unroll
  for (int i=0;i<4;i++)
    #pragma unroll
    for (int j=0;j<4;j++) acc[i][j] = (float4v){0.f,0.f,0.f,0.f};

  const unsigned short* Ap = A + (long)(m0+sm)*K + sq;
  const unsigned short* Bp = Bt + (long)(n0+sm)*K + sq;
  const long rstep = (long)64*K;

  for (int k0 = 0; k0 < K; k0 += 32){
    uint4 a0 = *(const uint4*)(Ap + k0);
    uint4 a1 = *(const uint4*)(Ap + k0 + rstep);
    uint4 b0 = *(const uint4*)(Bp + k0);
    uint4 b1 = *(const uint4*)(Bp + k0 + rstep);
    __syncthreads();
    *(uint4*)&As[sm   ][sq] = a0;
    *(uint4*)&As[sm+64][sq] = a1;
    *(uint4*)&Bs[sm   ][sq] = b0;
    *(uint4*)&Bs[sm+64][sq] = b1;
    __syncthreads();
    short8 af[4], bf[4];
    #pragma unroll
    for (int mt=0;mt<4;mt++) af[mt] = *(const short8*)&As[wm + mt*16 + r][q*8];
    #pragma unroll
    for (int nt=0;nt<4;nt++) bf[nt] = *(const short8*)&Bs[wn + nt*16 + r][q*8];
    #pragma unroll
    for (int mt=0;mt<4;mt++)
      #pragma unroll
      for (int nt=0;nt<4;nt++)
        acc[mt][nt] = __builtin_amdgcn_mfma_f32_16x16x32_bf16(af[mt], bf[nt], acc[mt][nt], 0, 0, 0);
  }

  #pragma unroll
  for (int nt=0;nt<4;nt++){
    int col = n0 + wn + nt*16 + r;
    float bb = bias[col];
    #pragma unroll
    for (int mt=0;mt<4;mt++){
      #pragma unroll
      for (int i=0;i<4;i++){
        int row = m0 + wm + mt*16 + q*4 + i;
        C[(long)row*N + col] = acc[mt][nt][i] + bb;
      }
    }
  }
}

// ================= psi1 MFMA: h1 += phi(x) @ Wpsi1, phi generated on the fly =================
// phi[m][d*64+k] = gelu(x[m,d]*Wphi[d,k]+bphi[d,k]).  BM=64, BN=64, split-K over 8 d-chunks of 32.
__global__ __launch_bounds__(256) void psi1m_k(const float* __restrict__ x,
    const float* __restrict__ Wphi, const float* __restrict__ bphi,
    const unsigned short* __restrict__ Wpsi1_t, float* __restrict__ h1)
{
  __shared__ float xs[64][33];                           // x tile [m][dd]
  __shared__ __align__(16) unsigned int wbls[32][64];    // packed (bphi<<16)|wphi per (dd,k)
  __shared__ __align__(16) unsigned short As[64][72];    // phi tile [m][k]
  __shared__ __align__(16) unsigned short Bs[64][72];    // Wpsi1_t tile [n][k]
  const int tid = threadIdx.x;
  const int m0 = blockIdx.x*64, d_lo = blockIdx.y*32;

  { // stage x: 64 m x 32 d
    int m = tid>>2, off = (tid&3)*8;
    const float* src = x + (long)(m0+m)*256 + d_lo + off;
    #pragma unroll
    for (int i=0;i<8;i++) xs[m][off+i] = src[i];
  }
  { // stage packed Wphi/bphi chunk: 32 d x 64 k
    #pragma unroll
    for (int i=0;i<2;i++){
      int idx4 = tid + 256*i;                 // 0..511 float4 groups
      int rr = idx4>>4, cc = (idx4&15)*4;
      float4 w4 = *(const float4*)&Wphi[(long)(d_lo+rr)*64 + cc];
      float4 b4 = *(const float4*)&bphi[(long)(d_lo+rr)*64 + cc];
      uint4 p;
      p.x = (unsigned int)f2b(w4.x) | ((unsigned int)f2b(b4.x)<<16);
      p.y = (unsigned int)f2b(w4.y) | ((unsigned int)f2b(b4.y)<<16);
      p.z = (unsigned int)f2b(w4.z) | ((unsigned int)f2b(b4.z)<<16);
      p.w = (unsigned int)f2b(w4.w) | ((unsigned int)f2b(b4.w)<<16);
      *(uint4*)&wbls[rr][cc] = p;
    }
  }
  const int wave = tid>>6, lane = tid&63;
  const int wm = (wave&1)*32, wn = (wave>>1)*32;
  const int q = lane>>4, r = lane&15;
  const int pm = tid>>2, pk = (tid&3)*16;     // phi compute: 16 k per thread
  const int bn = tid>>2, bk = (tid&3)*16;     // Bs staging

  float4v acc[2][2];
  #pragma unroll
  for (int i=0;i<2;i++)
    #pragma unroll
    for (int j=0;j<2;j++) acc[i][j] = (float4v){0.f,0.f,0.f,0.f};

  __syncthreads();

  for (int dd=0; dd<32; dd++){
    int dglob = d_lo + dd;
    const unsigned short* wp = Wpsi1_t + (long)bn*16384 + (long)dglob*64 + bk;
    uint4 b0 = *(const uint4*)wp;
    uint4 b1 = *(const uint4*)(wp + 8);
    float xv = xs[pm][dd];
    ushort4 ph[4];
    #pragma unroll
    for (int kk=0; kk<4; kk++){
      uint4 wb = *(const uint4*)&wbls[dd][pk + kk*4];
      unsigned int u[4] = {wb.x, wb.y, wb.z, wb.w};
      unsigned short o[4];
      #pragma unroll
      for (int e=0;e<4;e++){
        float w = u16tof((unsigned short)(u[e] & 0xffffu));
        float b = u16tof((unsigned short)(u[e] >> 16));
        o[e] = f2b(gelu_f(fmaf(xv, w, b)));
      }
      ph[kk].x=o[0]; ph[kk].y=o[1]; ph[kk].z=o[2]; ph[kk].w=o[3];
    }
    __syncthreads();                          // prev iter frag reads done
    *(uint4*)&Bs[bn][bk]   = b0;
    *(uint4*)&Bs[bn][bk+8] = b1;
    #pragma unroll
    for (int kk=0;kk<4;kk++) *(ushort4*)&As[pm][pk+kk*4] = ph[kk];
    __syncthreads();
    #pragma unroll
    for (int kb=0; kb<2; kb++){
      short8 af[2], bfr[2];
      #pragma unroll
      for (int mt=0;mt<2;mt++) af[mt]  = *(const short8*)&As[wm+mt*16+r][kb*32 + q*8];
      #pragma unroll
      for (int nt=0;nt<2;nt++) bfr[nt] = *(const short8*)&Bs[wn+nt*16+r][kb*32 + q*8];
      #pragma unroll
      for (int mt=0;mt<2;mt++)
        #pragma unroll
        for (int nt=0;nt<2;nt++)
          acc[mt][nt] = __builtin_amdgcn_mfma_f32_16x16x32_bf16(af[mt], bfr[nt], acc[mt][nt], 0, 0, 0);
    }
  }
  #pragma unroll
  for (int nt=0;nt<2;nt++){
    int col = wn + nt*16 + r;
    #pragma unroll
    for (int mt=0;mt<2;mt++)
      #pragma unroll
      for (int i=0;i<4;i++){
        int row = m0 + wm + mt*16 + q*4 + i;
        atomicAdd(&h1[(long)row*64 + col], acc[mt][nt][i]);
      }
  }
}

// ================= convert helpers =================
__global__ __launch_bounds__(256) void cvtb_k(const float* __restrict__ in, unsigned short* __restrict__ out){
  int i = (blockIdx.x*256 + threadIdx.x)*4;
  float4 v = *(const float4*)(in + i);
  ushort4 o; o.x = f2b(v.x); o.y = f2b(v.y); o.z = f2b(v.z); o.w = f2b(v.w);
  *(ushort4*)(out + i) = o;
}

// transpose-convert: in[R][C] f32 -> out[C][R] bf16   grid (C/64, R/64)
__global__ __launch_bounds__(256) void tconv_k(const float* __restrict__ in, unsigned short* __restrict__ out, int R, int C){
  __shared__ float t[64][65];
  const int tid = threadIdx.x;
  const int c0 = blockIdx.x*64, r0 = blockIdx.y*64;
  const int lr = tid>>2, lc0 = (tid&3)*16;
  #pragma unroll
  for (int i=0;i<4;i++){
    float4 v = *(const float4*)&in[(long)(r0+lr)*C + c0 + lc0 + i*4];
    t[lr][lc0+i*4+0]=v.x; t[lr][lc0+i*4+1]=v.y; t[lr][lc0+i*4+2]=v.z; t[lr][lc0+i*4+3]=v.w;
  }
  __syncthreads();
  const int oc = tid>>2, os = (tid&3)*16;
  #pragma unroll
  for (int i=0;i<16;i++)
    out[(long)(c0+oc)*R + r0 + os + i] = f2b(t[os+i][oc]);
}

// ================= SIMT fp32 GEMM (small shapes) =================
__device__ __forceinline__ float4 ld4(const float* p){ return *(const float4*)p; }
__device__ __forceinline__ float4 ld4(const unsigned short* p){
  ushort4 u = *(const ushort4*)p;
  return make_float4(u16tof(u.x), u16tof(u.y), u16tof(u.z), u16tof(u.w));
}
template<typename AT, int MODE>   // MODE 0 plain; MODE 2 split-K atomics
__global__ __launch_bounds__(256) void gemm_k(
    const AT* __restrict__ A, const float* __restrict__ B, const float* __restrict__ bias,
    float* __restrict__ C, int M, int N, int K, int Kc)
{
  int klo = 0, khi = K;
  if constexpr (MODE==2){ klo = blockIdx.z*Kc; khi = klo + Kc; }
  __shared__ __align__(16) float As[16][68];
  __shared__ __align__(16) float Bs[16][68];
  const int tid = threadIdx.x;
  const int m0 = blockIdx.y*64, n0 = blockIdx.x*64;
  const int ty = tid>>4, tx = tid&15;
  const int ar = tid>>2, ac = (tid&3)*4;
  const int kr = tid>>4, nc = (tid&15)*4;
  float acc[4][4] = {};
  const AT* Ap = A + (long)(m0+ar)*K;

  for (int k0 = klo; k0 < khi; k0 += 16){
    float4 av = ld4(Ap + k0 + ac);
    float4 bv = *(const float4*)(B + (long)(k0+kr)*N + (n0+nc));
    __syncthreads();
    As[ac+0][ar] = av.x; As[ac+1][ar] = av.y; As[ac+2][ar] = av.z; As[ac+3][ar] = av.w;
    *(float4*)&Bs[kr][nc] = bv;
    __syncthreads();
    #pragma unroll
    for (int k = 0; k < 16; k++){
      float4 a4 = *(const float4*)&As[k][ty*4];
      float4 b4 = *(const float4*)&Bs[k][tx*4];
      float a[4] = {a4.x,a4.y,a4.z,a4.w};
      float b[4] = {b4.x,b4.y,b4.z,b4.w};
      #pragma unroll
      for (int i = 0; i < 4; i++)
        #pragma unroll
        for (int j = 0; j < 4; j++)
          acc[i][j] = fmaf(a[i], b[j], acc[i][j]);
    }
  }
  float bv4[4];
  #pragma unroll
  for (int j = 0; j < 4; j++) bv4[j] = bias[n0 + tx*4 + j];
  #pragma unroll
  for (int i = 0; i < 4; i++){
    long row = m0 + ty*4 + i;
    #pragma unroll
    for (int j = 0; j < 4; j++){
      float v = acc[i][j];
      if constexpr (MODE==2){
        if (blockIdx.z == 0) v += bv4[j];
        atomicAdd(&C[row*(long)N + n0 + tx*4 + j], v);
      } else {
        C[row*(long)N + n0 + tx*4 + j] = v + bv4[j];
      }
    }
  }
}

// ---------- column mean over 4096 rows of adapt[4096,128] ----------
__global__ __launch_bounds__(256) void colmean_k(const float* __restrict__ adapt, float* __restrict__ am){
  __shared__ float red[256];
  int a = blockIdx.x, tid = threadIdx.x;
  float s = 0.f;
  for (int n = tid; n < 4096; n += 256) s += adapt[n*128 + a];
  red[tid] = s; __syncthreads();
  for (int w = 128; w > 0; w >>= 1){ if (tid < w) red[tid] += red[tid+w]; __syncthreads(); }
  if (tid == 0) am[a] = red[0] * (1.0f/4096.0f);
}

// ---------- gate = softmax(adapt @ Wg + bg) ----------
__global__ __launch_bounds__(256) void gate_k(const float* __restrict__ adapt,
    const float* __restrict__ Wg, const float* __restrict__ bg, float* __restrict__ gate){
  __shared__ float wg[640]; __shared__ float bgs[5];
  int tid = threadIdx.x;
  for (int i = tid; i < 640; i += 256) wg[i] = Wg[i];
  if (tid < 5) bgs[tid] = bg[tid];
  __syncthreads();
  int n = blockIdx.x*256 + tid;
  float l[5] = {bgs[0],bgs[1],bgs[2],bgs[3],bgs[4]};
  const float* ar = adapt + (long)n*128;
  for (int a = 0; a < 128; a++){
    float av = ar[a];
    #pragma unroll
    for (int e = 0; e < 5; e++) l[e] = fmaf(av, wg[a*5+e], l[e]);
  }
  float mx = l[0];
  #pragma unroll
  for (int e = 1; e < 5; e++) mx = fmaxf(mx, l[e]);
  float sum = 0.f;
  #pragma unroll
  for (int e = 0; e < 5; e++){ l[e] = expf(l[e]-mx); sum += l[e]; }
  float inv = 1.0f/sum;
  #pragma unroll
  for (int e = 0; e < 5; e++) gate[(long)n*5+e] = l[e]*inv;
}

// ---------- dynamic weights -> bf16 TRANSPOSED: Wdyn_t[z][out][in] ----------
__global__ __launch_bounds__(256) void dynw_k(const float* __restrict__ am,
    const float* Wt, const float* Wt_a, const float* bt_a,
    const float* Wc, const float* Wc_a, const float* bc_a,
    const float* We, const float* We_a, const float* be_a,
    unsigned short* __restrict__ Wdyn_t)
{
  __shared__ float ams[128];
  int tid = threadIdx.x;
  if (tid < 128) ams[tid] = am[tid];
  __syncthreads();
  long gid = (long)blockIdx.x*256 + tid;
  int seg = (int)(gid >> 16); int m = (int)(gid & 65535);
  const float *W, *Wa, *ba;
  if (seg == 0){ W = Wt; Wa = Wt_a; ba = bt_a; }
  else if (seg == 1){ W = Wc; Wa = Wc_a; ba = bc_a; }
  else { int e = seg-2; W = We + (long)e*65536; Wa = We_a + (long)e*65536*128; ba = be_a + (long)e*65536; }
  float s = W[m] + ba[m];
  for (int a = 0; a < 128; a++) s = fmaf(ams[a], Wa[(long)a*65536 + m], s);
  int row = m >> 8, col = m & 255;
  Wdyn_t[(long)seg*65536 + (long)col*256 + row] = f2b(s);
}

// ---------- bias table ----------
__global__ void bias6_k(const float* bt, const float* bc, const float* be, float* bias6){
  int z = blockIdx.x, t = threadIdx.x;
  const float* s = (z==0) ? bt : (z==1) ? bc : be + (long)(z-2)*256;
  bias6[z*256 + t] = s[t];
}

// ---------- h1g = gelu(h1 + bpsi1) ----------
__global__ __launch_bounds__(256) void h1g_k(const float* __restrict__ h1,
    const float* __restrict__ bpsi1, float* __restrict__ h1g){
  int i = blockIdx.x*256 + threadIdx.x;
  h1g[i] = gelu_f(h1[i] + bpsi1[i & 63]);
}

// ---------- concat -> bf16 [tok | chan | moe | lf] ----------
__global__ __launch_bounds__(256) void concat_k(const float* __restrict__ tok,
    const float* __restrict__ chan, const float* __restrict__ eo,
    const float* __restrict__ gate, const float* __restrict__ ka,
    const float* __restrict__ lf, unsigned short* __restrict__ concat)
{
  int n = blockIdx.x, tid = threadIdx.x;
  const float* g = gate + (long)n*5;
  float g0=g[0], g1=g[1], g2=g[2], g3=g[3], g4=g[4];
  long nb = (long)n*1536;
  int d = tid;
  concat[nb + d]        = f2b(tok[(long)n*256 + d]);
  concat[nb + 256 + d]  = f2b(chan[(long)n*256 + d]);
  float m = g0*eo[(long)n*256 + d]
          + g1*eo[1048576 + (long)n*256 + d]
          + g2*eo[2097152 + (long)n*256 + d]
          + g3*eo[3145728 + (long)n*256 + d]
          + g4*ka[(long)n*256 + d];
  concat[nb + 512 + d] = f2b(m);
  for (int j = tid; j < 768; j += 256) concat[nb + 768 + j] = f2b(lf[(long)n*768 + j]);
}

// ---------- cw = softmax( gelu(h_pre) @ W2 + b2 ) ----------
__global__ __launch_bounds__(256) void cw_k(const float* __restrict__ hpre,
    const float* __restrict__ W2, const float* __restrict__ b2, float* __restrict__ cw){
  __shared__ float w2s[256]; __shared__ float b2s[4];
  int tid = threadIdx.x;
  w2s[tid] = W2[tid];
  if (tid < 4) b2s[tid] = b2[tid];
  __syncthreads();
  int n = blockIdx.x*256 + tid;
  float l[4] = {b2s[0],b2s[1],b2s[2],b2s[3]};
  const float* hp = hpre + (long)n*64;
  for (int j = 0; j < 64; j++){
    float hj = gelu_f(hp[j]);
    #pragma unroll
    for (int c = 0; c < 4; c++) l[c] = fmaf(hj, w2s[j*4+c], l[c]);
  }
  float mx = fmaxf(fmaxf(l[0],l[1]), fmaxf(l[2],l[3]));
  float sum = 0.f;
  #pragma unroll
  for (int c = 0; c < 4; c++){ l[c] = expf(l[c]-mx); sum += l[c]; }
  float inv = 1.0f/sum;
  #pragma unroll
  for (int c = 0; c < 4; c++) cw[(long)n*4+c] = l[c]*inv;
}

// ---------- combined (in-place bf16) ----------
__global__ __launch_bounds__(256) void combine_k(unsigned short* __restrict__ concat,
    const float* __restrict__ residual, const float* __restrict__ cw){
  int n = blockIdx.x;
  int j = blockIdx.y*256 + threadIdx.x;
  int seg = (j < 768) ? (j >> 8) : 3;
  long idx = (long)n*1536 + j;
  float v = fmaf(cw[(long)n*4 + seg], u16tof(concat[idx]), residual[idx]);
  concat[idx] = f2b(v);
}

// ---------- launch ----------
extern "C" void kernel_launch(void* const* d_in, const int* in_sizes, int n_in,
                              void* d_out, int out_size, void* d_ws, size_t ws_size,
                              hipStream_t stream)
{
  const float* x      = (const float*)d_in[0];
  const float* lf     = (const float*)d_in[1];
  const float* W_feat = (const float*)d_in[2];
  const float* b_feat = (const float*)d_in[3];
  const float* Wt     = (const float*)d_in[4];
  const float* bt     = (const float*)d_in[5];
  const float* Wt_a   = (const float*)d_in[6];
  const float* bt_a   = (const float*)d_in[7];
  const float* Wc     = (const float*)d_in[8];
  const float* bc     = (const float*)d_in[9];
  const float* Wc_a   = (const float*)d_in[10];
  const float* bc_a   = (const float*)d_in[11];
  const float* We     = (const float*)d_in[12];
  const float* be     = (const float*)d_in[13];
  const float* We_a   = (const float*)d_in[14];
  const float* be_a   = (const float*)d_in[15];
  const float* Wg     = (const float*)d_in[16];
  const float* bg     = (const float*)d_in[17];
  const float* Wphi   = (const float*)d_in[18];
  const float* bphi   = (const float*)d_in[19];
  const float* Wpsi1  = (const float*)d_in[20];
  const float* bpsi1  = (const float*)d_in[21];
  const float* Wpsi2  = (const float*)d_in[22];
  const float* bpsi2  = (const float*)d_in[23];
  const float* Wres   = (const float*)d_in[24];
  const float* bres   = (const float*)d_in[25];
  const float* W1     = (const float*)d_in[26];
  const float* b1     = (const float*)d_in[27];
  const float* W2     = (const float*)d_in[28];
  const float* b2     = (const float*)d_in[29];
  const float* Wo     = (const float*)d_in[30];
  const float* bo     = (const float*)d_in[31];

  float* ws = (float*)d_ws;
  float* T      = ws;                        // 6,291,456 f32 : tok|chan|eo[0..3]
  float* tok    = T;
  float* chan   = T + 1048576;
  float* eo     = T + 2*1048576;
  float* adapt  = T + 6*1048576;             // 524,288
  float* am     = adapt + 524288;            // 128
  float* gate   = am + 128;                  // 20,480
  float* bias6  = gate + 20480;              // 1,536
  float* h1     = bias6 + 1536;              // 262,144
  float* h1g    = h1 + 262144;               // 262,144
  float* ka     = h1g + 262144;              // 1,048,576
  unsigned short* xb      = (unsigned short*)(ka + 1048576);  // 1,048,576 u16
  unsigned short* Wdyn_t  = xb + 1048576;                     // 393,216 u16
  unsigned short* Wres_t  = Wdyn_t + 393216;                  // 2,359,296 u16
  unsigned short* Wo_t    = Wres_t + 2359296;                 // 393,216 u16
  unsigned short* Wpsi1_t = Wo_t + 393216;                    // 1,048,576 u16
  unsigned short* concat  = Wpsi1_t + 1048576;                // 6,291,456 u16
  float* residual = T;                       // alias: tok/chan/eo dead after concat_k
  float* hpre   = adapt;                     // alias: adapt dead after colmean/gate
  float* cw     = adapt + 262144;            // alias

  dim3 b256(256);

  // converts
  cvtb_k<<<dim3(1024), b256, 0, stream>>>(x, xb);
  tconv_k<<<dim3(24,24), b256, 0, stream>>>(Wres, Wres_t, 1536, 1536);
  tconv_k<<<dim3(4,24),  b256, 0, stream>>>(Wo,   Wo_t,   1536, 256);
  tconv_k<<<dim3(1,256), b256, 0, stream>>>(Wpsi1, Wpsi1_t, 16384, 64);

  // adapt = x @ W_feat + b_feat (fp32 SIMT for am precision)
  gemm_k<float,0><<<dim3(2,64,1), b256, 0, stream>>>(x, W_feat, b_feat, adapt, 4096,128,256, 0);

  colmean_k<<<dim3(128), b256, 0, stream>>>(adapt, am);
  gate_k<<<dim3(16), b256, 0, stream>>>(adapt, Wg, bg, gate);

  dynw_k<<<dim3(1536), b256, 0, stream>>>(am, Wt,Wt_a,bt_a, Wc,Wc_a,bc_a, We,We_a,be_a, Wdyn_t);
  bias6_k<<<dim3(6), b256, 0, stream>>>(bt, bc, be, bias6);

  // tok/chan/eo[z] = xb @ Wdyn_t[z]^T + bias6[z]   MFMA batched
  mgemm_k<1><<<dim3(2,32,6), b256, 0, stream>>>(xb, Wdyn_t, bias6, T, 4096,256,256, 65536,256,1048576);

  // KA expert: psi1 via fused-phi MFMA (split-K over 8 d-chunks, atomics)
  hipMemsetAsync(h1, 0, 262144*sizeof(float), stream);
  psi1m_k<<<dim3(64,8), b256, 0, stream>>>(x, Wphi, bphi, Wpsi1_t, h1);
  h1g_k<<<dim3(1024), b256, 0, stream>>>(h1, bpsi1, h1g);
  gemm_k<float,0><<<dim3(4,64,1), b256, 0, stream>>>(h1g, Wpsi2, bpsi2, ka, 4096,256,64, 0);

  concat_k<<<dim3(4096), b256, 0, stream>>>(tok, chan, eo, gate, ka, lf, concat);

  // residual = concat @ Wres + bres   MFMA
  mgemm_k<0><<<dim3(12,32,1), b256, 0, stream>>>(concat, Wres_t, bres, residual, 4096,1536,1536, 0,0,0);

  // h_pre = concat @ W1 + b1 (SIMT split-K=8; gelu folded into cw_k)
  hipMemsetAsync(hpre, 0, 262144*sizeof(float), stream);
  gemm_k<unsigned short,2><<<dim3(1,64,8), b256, 0, stream>>>(concat, W1, b1, hpre, 4096,64,1536, 192);
  cw_k<<<dim3(16), b256, 0, stream>>>(hpre, W2, b2, cw);

  combine_k<<<dim3(4096,6), b256, 0, stream>>>(concat, residual, cw);

  // out = combined @ Wo + bo   MFMA
  mgemm_k<0><<<dim3(2,32,1), b256, 0, stream>>>(concat, Wo_t, bo, (float*)d_out, 4096,256,1536, 0,0,0);
}